// Round 2
// baseline (307.093 us; speedup 1.0000x reference)
//
#include <hip/hip_runtime.h>
#include <hip/hip_cooperative_groups.h>
#include <math.h>

namespace cg = cooperative_groups;

typedef __bf16 v8bf __attribute__((ext_vector_type(8)));
typedef float  v4f  __attribute__((ext_vector_type(4)));

constexpr int Bsz  = 8;
constexpr int Cch  = 32;
constexpr int WIMG = 128;
constexpr int OH   = 64;
constexpr int OW   = 64;
constexpr int INCH = 201;
constexpr int KP   = 224;
constexpr int NK   = 7;
constexpr int OUTCH = 1152;
constexpr int MTOT = Bsz * OH * OW;   // 32768
constexpr float BN_EPS = 1e-5f;

// ws layout
constexpr size_t WT_BYTES = (size_t)NK * OUTCH * 32 * 2;   // 516,096
constexpr size_t BIAS_OFF = WT_BYTES;
constexpr size_t FEAT_OFF = BIAS_OFF + OUTCH * 4;          // 520,704 (16-aligned)

// ---- async global->LDS (wave-uniform base + lane*16 contiguous) ----
typedef const void __attribute__((address_space(1)))* gas_ptr;
typedef void __attribute__((address_space(3)))* las_ptr;
__device__ __forceinline__ void load16_lds(const void* g, void* l) {
    __builtin_amdgcn_global_load_lds((gas_ptr)(uintptr_t)g, (las_ptr)(uintptr_t)l, 16, 0, 0);
}

constexpr int SXS = 132;            // padded sx row stride (floats)
constexpr int FEAT_BLOCKS = Bsz * OH;        // 512
constexpr int NPREP = OUTCH * KP + OUTCH;    // 259,200
constexpr int PREP_BLOCKS = (NPREP + 255) / 256;

// LDS carve-up (fused kernel): phase A uses 80,944 B; phase B views alias it.
constexpr int SX_OFF    = 0;                       // 50,688 B (float)
constexpr int CMAX_OFF  = 50688;                   //  1,584 B (float)
constexpr int SFEAT_OFF = 52272;                   // 28,672 B (bf16)
constexpr int LDS_BYTES = 80944;                   // <= 81,920 -> 2 blocks/CU
// phase B: A dbuf @0 (2x16,384), B dbuf @32,768 (2x9,216) = 51,200 B
constexpr int YS  = 148;            // epilogue y row stride (floats)
constexpr int REG = 16 * YS;        // per-wave y region = 9,472 B (4 waves = 37,888)

// ---------------------------------------------------------------------------
// Fused kernel: phase A (Wt/bias prep + feat) -> grid sync -> phase B (gemm).
// 512 blocks x 256 thr = exactly 2 blocks/CU x 256 CU (cooperative).
// ---------------------------------------------------------------------------
__global__ __launch_bounds__(256, 2)
void fused_kernel(const float* __restrict__ x,
                  const float* __restrict__ conv_w,
                  const float* __restrict__ gamma,
                  const float* __restrict__ beta,
                  const float* __restrict__ mean,
                  const float* __restrict__ var,
                  __bf16* __restrict__ Wt,
                  float* __restrict__ biasp,
                  __bf16* __restrict__ feat,
                  float* __restrict__ out) {
    __shared__ __align__(16) unsigned char lds[LDS_BYTES];

    const int t   = threadIdx.x;
    const int bid = (int)blockIdx.x;

    // ================= Phase A0: Wt / bias prep (grid-strided) =============
    {
        const int nW = OUTCH * KP;
        for (int idx = bid * 256 + t; idx < NPREP; idx += 512 * 256) {
            if (idx < nW) {
                int o = idx / KP;
                int f = idx - o * KP;
                float inv = gamma[o] * rsqrtf(var[o] + BN_EPS);
                float v = (f < INCH) ? conv_w[o * INCH + f] * inv : 0.0f;
                Wt[((size_t)(f >> 5) * OUTCH + o) * 32 + (f & 31)] = (__bf16)v;
            } else {
                int o = idx - nW;
                float inv = gamma[o] * rsqrtf(var[o] + BN_EPS);
                biasp[o] = beta[o] - mean[o] * inv;
            }
        }
    }

    // ================= Phase A1: feat for (b, ho) ==========================
    {
        float*  sx    = (float*)(lds + SX_OFF);
        float*  cmax  = (float*)(lds + CMAX_OFF);
        __bf16* sfeat = (__bf16*)(lds + SFEAT_OFF);

        const int b  = bid >> 6;
        const int ho = bid & 63;

        // stage 1: float4 loads (12/thread), 3 rows x 32 ch
        for (int idx = t; idx < Cch * 3 * 32; idx += 256) {
            int c   = idx / 96;
            int rem = idx - c * 96;
            int i   = rem >> 5;
            int q   = rem & 31;
            int r   = 2 * ho - 1 + i;
            float4 v = make_float4(0.f, 0.f, 0.f, 0.f);
            if (r >= 0 && r < WIMG)
                v = *(const float4*)(x + (((size_t)(b * Cch + c) * WIMG) + r) * WIMG + q * 4);
            float* dst = sx + (c * 3 + i) * SXS + q * 4 + 1;
            dst[0] = v.x; dst[1] = v.y; dst[2] = v.z; dst[3] = v.w;
        }
        if (t < 96) {
            float* row = sx + t * SXS;
            row[0] = 0.0f; row[129] = 0.0f; row[130] = 0.0f; row[131] = 0.0f;
        }
        __syncthreads();

        if (t < 99) {     // column max over 32 channels (x1 source)
            int i = t / 33, cg2 = t - i * 33;
            const float4* base = (const float4*)sx + i * (SXS / 4) + cg2;
            float4 m = base[0];
            #pragma unroll 4
            for (int c = 1; c < Cch; ++c) {
                float4 v = base[(size_t)c * (3 * SXS / 4)];
                m.x = fmaxf(m.x, v.x); m.y = fmaxf(m.y, v.y);
                m.z = fmaxf(m.z, v.z); m.w = fmaxf(m.w, v.w);
            }
            ((float4*)cmax)[i * (SXS / 4) + cg2] = m;
        }
        __syncthreads();

        for (int idx = t; idx < 9 * 64; idx += 256) {     // x1
            int f = idx >> 6, wo = idx & 63;
            int i = f / 3, j = f - 3 * i;
            sfeat[wo * 32 + f] = (__bf16)cmax[i * SXS + 2 * wo + j];
        }
        {   // x2/x3
            const int wp = t & 31, g = t >> 5;
            const int wo0 = 2 * wp;
            #pragma unroll
            for (int cl = 0; cl < 4; ++cl) {
                int c = g * 4 + cl;
                float v[3][5];
                #pragma unroll
                for (int i = 0; i < 3; ++i) {
                    const float* row = sx + (c * 3 + i) * SXS + 4 * wp;
                    float4 q = *(const float4*)row;
                    v[i][0] = q.x; v[i][1] = q.y; v[i][2] = q.z; v[i][3] = q.w;
                    v[i][4] = row[4];
                }
                #pragma unroll
                for (int i = 0; i < 3; ++i) {            // x3
                    int f = 105 + c * 3 + i;
                    float a0 = fmaxf(fmaxf(v[i][0], v[i][1]), v[i][2]);
                    float a1 = fmaxf(fmaxf(v[i][2], v[i][3]), v[i][4]);
                    sfeat[(f >> 5) * 2048 + wo0 * 32 + (f & 31)]       = (__bf16)a0;
                    sfeat[(f >> 5) * 2048 + (wo0 + 1) * 32 + (f & 31)] = (__bf16)a1;
                }
                #pragma unroll
                for (int j = 0; j < 3; ++j) {            // x2
                    int f = 9 + c * 3 + j;
                    float a0 = fmaxf(fmaxf(v[0][j], v[1][j]), v[2][j]);
                    float a1 = fmaxf(fmaxf(v[0][j + 2], v[1][j + 2]), v[2][j + 2]);
                    sfeat[(f >> 5) * 2048 + wo0 * 32 + (f & 31)]       = (__bf16)a0;
                    sfeat[(f >> 5) * 2048 + (wo0 + 1) * 32 + (f & 31)] = (__bf16)a1;
                }
            }
        }
        for (int idx = t; idx < 64 * 23; idx += 256) {   // K padding
            int wo = idx / 23, fo = idx - wo * 23;
            int f = 201 + fo;
            sfeat[6 * 2048 + wo * 32 + (f & 31)] = (__bf16)0.0f;
        }
        __syncthreads();

        const size_t spat0 = (size_t)(b * OH + ho) * OW;
        #pragma unroll
        for (int kc = 0; kc < NK; ++kc) {
            float4 vv = ((const float4*)sfeat)[kc * 256 + t];
            ((float4*)((char*)feat + ((size_t)kc * MTOT + spat0) * 64))[t] = vv;
        }
    }

    // ============ hand-off: device-scope release, grid barrier, acquire ====
    __threadfence();             // agent-scope: wbl2 on writer XCDs
    cg::this_grid().sync();
    __threadfence();             // agent-scope: inv on reader XCDs

    // ================= Phase B: gemm, 2 tiles per block ====================
    const int wave = t >> 6, lane = t & 63, quad = lane >> 4, l16 = lane & 15;

    #pragma unroll 1
    for (int tile = 0; tile < 2; ++tile) {
        const int tg = bid + tile * 512;       // same mb both tiles, same XCD
        const int nb = tg >> 7;                // 0..7
        const int mb = tg & 127;               // 0..127
        const int M0 = mb * 256;
        const int N0 = nb * 144;

        auto issue = [&](int ks, int buf) {
            const char* Ag = (const char*)feat + ((size_t)ks * MTOT + M0) * 64;
            char* Ab = (char*)lds + buf * 16384;
            #pragma unroll
            for (int i = 0; i < 4; ++i) {
                int off = (wave * 4 + i) * 1024 + lane * 16;
                load16_lds(Ag + off, Ab + off);
            }
            const char* Bg = (const char*)Wt + ((size_t)ks * OUTCH + N0) * 64;
            char* Bb = (char*)lds + 32768 + buf * 9216;
            #pragma unroll
            for (int i = 0; i < 2; ++i) {
                int off = (wave * 2 + i) * 1024 + lane * 16;
                load16_lds(Bg + off, Bb + off);
            }
            if (wave == 0) {
                int off2 = 8192 + lane * 16;
                load16_lds(Bg + off2, Bb + off2);
            }
        };

        v4f acc[4][9];
        #pragma unroll
        for (int mt = 0; mt < 4; ++mt)
            #pragma unroll
            for (int nt = 0; nt < 9; ++nt)
                acc[mt][nt] = (v4f){0.f, 0.f, 0.f, 0.f};

        issue(0, 0);
        __syncthreads();

        for (int ks = 0; ks < NK; ++ks) {
            const int cur = ks & 1;
            if (ks + 1 < NK) issue(ks + 1, cur ^ 1);

            const char* Ab = (const char*)lds + cur * 16384;
            const char* Bb = (const char*)lds + 32768 + cur * 9216;
            v8bf af[4];
            #pragma unroll
            for (int mt = 0; mt < 4; ++mt)
                af[mt] = *(const v8bf*)(Ab + (wave * 64 + mt * 16 + l16) * 64 + quad * 16);
            #pragma unroll
            for (int nt = 0; nt < 9; ++nt) {
                v8bf bf = *(const v8bf*)(Bb + (nt * 16 + l16) * 64 + quad * 16);
                #pragma unroll
                for (int mt = 0; mt < 4; ++mt)
                    acc[mt][nt] = __builtin_amdgcn_mfma_f32_16x16x32_bf16(
                        af[mt], bf, acc[mt][nt], 0, 0, 0);
            }
            __syncthreads();   // drains global_load_lds + guards dbuf reuse
        }

        // ---- epilogue: per-wave private transpose; no cross-wave barriers ----
        float bia[9];
        #pragma unroll
        for (int nt = 0; nt < 9; ++nt) bia[nt] = biasp[N0 + nt * 16 + l16];

        float* yw = (float*)lds + wave * REG;        // private [16][YS]
        const int cl  = lane >> 4;                   // 0..3 channel-sub
        const int wl  = lane & 15;                   // wo within 16-block
        const int cg2 = nb * 4 + cl;
        const float s9 = 1.0f / 9.0f;

        #pragma unroll
        for (int p = 0; p < 4; ++p) {
            #pragma unroll
            for (int nt = 0; nt < 9; ++nt)
                #pragma unroll
                for (int r = 0; r < 4; ++r)
                    yw[(quad * 4 + r) * YS + nt * 16 + l16] =
                        fmaxf(acc[p][nt][r] + bia[nt], 0.0f);

            const int mg  = M0 + wave * 64 + p * 16 + wl;
            const int bb  = mg >> 12;
            const int hob = (mg >> 6) & 63;
            const int wo  = mg & 63;
            const float* xc = x + (size_t)(bb * Cch + cg2) * WIMG * WIMG;

            float pt[9];
            #pragma unroll
            for (int qi = 0; qi < 3; ++qi) {
                int r = 2 * hob - 1 + qi;
                #pragma unroll
                for (int qj = 0; qj < 3; ++qj) {
                    int col = 2 * wo - 1 + qj;
                    float v = 0.0f;
                    if (r >= 0 && r < WIMG && col >= 0 && col < WIMG)
                        v = xc[r * WIMG + col];
                    pt[qi * 3 + qj] = v;
                }
            }
            const float4* yrow = (const float4*)(yw + wl * YS + cl * 36);
            float o00 = 0.f, o01 = 0.f, o10 = 0.f, o11 = 0.f;
            #pragma unroll
            for (int q = 0; q < 9; ++q) {
                float4 yv = yrow[q];
                float pq = pt[q];
                o00 = fmaf(pq, yv.x, o00);
                o01 = fmaf(pq, yv.y, o01);
                o10 = fmaf(pq, yv.z, o10);
                o11 = fmaf(pq, yv.w, o11);
            }
            size_t obase = (((size_t)(bb * Cch + cg2) * WIMG) + 2 * hob) * WIMG + 2 * wo;
            *(float2*)(out + obase)        = make_float2(o00 * s9, o01 * s9);
            *(float2*)(out + obase + WIMG) = make_float2(o10 * s9, o11 * s9);
        }
        __syncthreads();   // all waves done with yw before next tile's issue()
    }
}

// ---------------------------------------------------------------------------
// Fallback path (two-kernel, identical to round-1 kernel) in case the
// cooperative launch is rejected by the runtime / graph capture.
// ---------------------------------------------------------------------------
__global__ __launch_bounds__(256)
void prep_feat_kernel(const float* __restrict__ x,
                      const float* __restrict__ conv_w,
                      const float* __restrict__ gamma,
                      const float* __restrict__ beta,
                      const float* __restrict__ mean,
                      const float* __restrict__ var,
                      __bf16* __restrict__ Wt,
                      float* __restrict__ biasp,
                      __bf16* __restrict__ feat) {
    __shared__ __align__(16) float sx[Cch * 3 * SXS];
    __shared__ __align__(16) float cmax[3 * SXS];
    __shared__ __align__(16) __bf16 sfeat[NK * OW * 32];

    const int t = threadIdx.x;

    if (blockIdx.x >= FEAT_BLOCKS) {
        int idx = ((int)blockIdx.x - FEAT_BLOCKS) * 256 + t;
        const int nW = OUTCH * KP;
        if (idx < nW) {
            int o = idx / KP;
            int f = idx - o * KP;
            float inv = gamma[o] * rsqrtf(var[o] + BN_EPS);
            float v = (f < INCH) ? conv_w[o * INCH + f] * inv : 0.0f;
            Wt[((size_t)(f >> 5) * OUTCH + o) * 32 + (f & 31)] = (__bf16)v;
        } else if (idx < nW + OUTCH) {
            int o = idx - nW;
            float inv = gamma[o] * rsqrtf(var[o] + BN_EPS);
            biasp[o] = beta[o] - mean[o] * inv;
        }
        return;
    }

    const int b  = blockIdx.x >> 6;
    const int ho = blockIdx.x & 63;

    for (int idx = t; idx < Cch * 3 * 32; idx += 256) {
        int c   = idx / 96;
        int rem = idx - c * 96;
        int i   = rem >> 5;
        int q   = rem & 31;
        int r   = 2 * ho - 1 + i;
        float4 v = make_float4(0.f, 0.f, 0.f, 0.f);
        if (r >= 0 && r < WIMG)
            v = *(const float4*)(x + (((size_t)(b * Cch + c) * WIMG) + r) * WIMG + q * 4);
        float* dst = sx + (c * 3 + i) * SXS + q * 4 + 1;
        dst[0] = v.x; dst[1] = v.y; dst[2] = v.z; dst[3] = v.w;
    }
    if (t < 96) {
        float* row = sx + t * SXS;
        row[0] = 0.0f; row[129] = 0.0f; row[130] = 0.0f; row[131] = 0.0f;
    }
    __syncthreads();

    if (t < 99) {
        int i = t / 33, cg2 = t - i * 33;
        const float4* base = (const float4*)sx + i * (SXS / 4) + cg2;
        float4 m = base[0];
        #pragma unroll 4
        for (int c = 1; c < Cch; ++c) {
            float4 v = base[(size_t)c * (3 * SXS / 4)];
            m.x = fmaxf(m.x, v.x); m.y = fmaxf(m.y, v.y);
            m.z = fmaxf(m.z, v.z); m.w = fmaxf(m.w, v.w);
        }
        ((float4*)cmax)[i * (SXS / 4) + cg2] = m;
    }
    __syncthreads();

    for (int idx = t; idx < 9 * 64; idx += 256) {
        int f = idx >> 6, wo = idx & 63;
        int i = f / 3, j = f - 3 * i;
        sfeat[wo * 32 + f] = (__bf16)cmax[i * SXS + 2 * wo + j];
    }
    {
        const int wp = t & 31, g = t >> 5;
        const int wo0 = 2 * wp;
        #pragma unroll
        for (int cl = 0; cl < 4; ++cl) {
            int c = g * 4 + cl;
            float v[3][5];
            #pragma unroll
            for (int i = 0; i < 3; ++i) {
                const float* row = sx + (c * 3 + i) * SXS + 4 * wp;
                float4 q = *(const float4*)row;
                v[i][0] = q.x; v[i][1] = q.y; v[i][2] = q.z; v[i][3] = q.w;
                v[i][4] = row[4];
            }
            #pragma unroll
            for (int i = 0; i < 3; ++i) {
                int f = 105 + c * 3 + i;
                float a0 = fmaxf(fmaxf(v[i][0], v[i][1]), v[i][2]);
                float a1 = fmaxf(fmaxf(v[i][2], v[i][3]), v[i][4]);
                sfeat[(f >> 5) * 2048 + wo0 * 32 + (f & 31)]       = (__bf16)a0;
                sfeat[(f >> 5) * 2048 + (wo0 + 1) * 32 + (f & 31)] = (__bf16)a1;
            }
            #pragma unroll
            for (int j = 0; j < 3; ++j) {
                int f = 9 + c * 3 + j;
                float a0 = fmaxf(fmaxf(v[0][j], v[1][j]), v[2][j]);
                float a1 = fmaxf(fmaxf(v[0][j + 2], v[1][j + 2]), v[2][j + 2]);
                sfeat[(f >> 5) * 2048 + wo0 * 32 + (f & 31)]       = (__bf16)a0;
                sfeat[(f >> 5) * 2048 + (wo0 + 1) * 32 + (f & 31)] = (__bf16)a1;
            }
        }
    }
    for (int idx = t; idx < 64 * 23; idx += 256) {
        int wo = idx / 23, fo = idx - wo * 23;
        int f = 201 + fo;
        sfeat[6 * 2048 + wo * 32 + (f & 31)] = (__bf16)0.0f;
    }
    __syncthreads();

    const size_t spat0 = (size_t)(b * OH + ho) * OW;
    #pragma unroll
    for (int kc = 0; kc < NK; ++kc) {
        float4 vv = ((const float4*)sfeat)[kc * 256 + t];
        ((float4*)((char*)feat + ((size_t)kc * MTOT + spat0) * 64))[t] = vv;
    }
}

__global__ __launch_bounds__(256, 2)
void gemm_kernel(const __bf16* __restrict__ feat,
                 const __bf16* __restrict__ Wt,
                 const float* __restrict__ biasp,
                 const float* __restrict__ x,
                 float* __restrict__ out) {
    __shared__ __align__(16) unsigned char lds[51200];

    const int t    = threadIdx.x;
    const int nb   = (int)blockIdx.x >> 7;
    const int mb   = (int)blockIdx.x & 127;
    const int M0   = mb * 256;
    const int N0   = nb * 144;
    const int wave = t >> 6, lane = t & 63, quad = lane >> 4, l16 = lane & 15;

    auto issue = [&](int ks, int buf) {
        const char* Ag = (const char*)feat + ((size_t)ks * MTOT + M0) * 64;
        char* Ab = (char*)lds + buf * 16384;
        #pragma unroll
        for (int i = 0; i < 4; ++i) {
            int off = (wave * 4 + i) * 1024 + lane * 16;
            load16_lds(Ag + off, Ab + off);
        }
        const char* Bg = (const char*)Wt + ((size_t)ks * OUTCH + N0) * 64;
        char* Bb = (char*)lds + 32768 + buf * 9216;
        #pragma unroll
        for (int i = 0; i < 2; ++i) {
            int off = (wave * 2 + i) * 1024 + lane * 16;
            load16_lds(Bg + off, Bb + off);
        }
        if (wave == 0) {
            int off2 = 8192 + lane * 16;
            load16_lds(Bg + off2, Bb + off2);
        }
    };

    v4f acc[4][9];
    #pragma unroll
    for (int mt = 0; mt < 4; ++mt)
        #pragma unroll
        for (int nt = 0; nt < 9; ++nt)
            acc[mt][nt] = (v4f){0.f, 0.f, 0.f, 0.f};

    issue(0, 0);
    __syncthreads();

    for (int ks = 0; ks < NK; ++ks) {
        const int cur = ks & 1;
        if (ks + 1 < NK) issue(ks + 1, cur ^ 1);

        const char* Ab = (const char*)lds + cur * 16384;
        const char* Bb = (const char*)lds + 32768 + cur * 9216;
        v8bf af[4];
        #pragma unroll
        for (int mt = 0; mt < 4; ++mt)
            af[mt] = *(const v8bf*)(Ab + (wave * 64 + mt * 16 + l16) * 64 + quad * 16);
        #pragma unroll
        for (int nt = 0; nt < 9; ++nt) {
            v8bf bf = *(const v8bf*)(Bb + (nt * 16 + l16) * 64 + quad * 16);
            #pragma unroll
            for (int mt = 0; mt < 4; ++mt)
                acc[mt][nt] = __builtin_amdgcn_mfma_f32_16x16x32_bf16(
                    af[mt], bf, acc[mt][nt], 0, 0, 0);
        }
        __syncthreads();
    }

    float bia[9];
    #pragma unroll
    for (int nt = 0; nt < 9; ++nt) bia[nt] = biasp[N0 + nt * 16 + l16];

    float* yw = (float*)lds + wave * REG;
    const int cl  = lane >> 4;
    const int wl  = lane & 15;
    const int cg2 = nb * 4 + cl;
    const float s9 = 1.0f / 9.0f;

    #pragma unroll
    for (int p = 0; p < 4; ++p) {
        #pragma unroll
        for (int nt = 0; nt < 9; ++nt)
            #pragma unroll
            for (int r = 0; r < 4; ++r)
                yw[(quad * 4 + r) * YS + nt * 16 + l16] =
                    fmaxf(acc[p][nt][r] + bia[nt], 0.0f);

        const int mg  = M0 + wave * 64 + p * 16 + wl;
        const int bb  = mg >> 12;
        const int hob = (mg >> 6) & 63;
        const int wo  = mg & 63;
        const float* xc = x + (size_t)(bb * Cch + cg2) * WIMG * WIMG;

        float pt[9];
        #pragma unroll
        for (int qi = 0; qi < 3; ++qi) {
            int r = 2 * hob - 1 + qi;
            #pragma unroll
            for (int qj = 0; qj < 3; ++qj) {
                int col = 2 * wo - 1 + qj;
                float v = 0.0f;
                if (r >= 0 && r < WIMG && col >= 0 && col < WIMG)
                    v = xc[r * WIMG + col];
                pt[qi * 3 + qj] = v;
            }
        }
        const float4* yrow = (const float4*)(yw + wl * YS + cl * 36);
        float o00 = 0.f, o01 = 0.f, o10 = 0.f, o11 = 0.f;
        #pragma unroll
        for (int q = 0; q < 9; ++q) {
            float4 yv = yrow[q];
            float pq = pt[q];
            o00 = fmaf(pq, yv.x, o00);
            o01 = fmaf(pq, yv.y, o01);
            o10 = fmaf(pq, yv.z, o10);
            o11 = fmaf(pq, yv.w, o11);
        }
        size_t obase = (((size_t)(bb * Cch + cg2) * WIMG) + 2 * hob) * WIMG + 2 * wo;
        *(float2*)(out + obase)        = make_float2(o00 * s9, o01 * s9);
        *(float2*)(out + obase + WIMG) = make_float2(o10 * s9, o11 * s9);
    }
}

extern "C" void kernel_launch(void* const* d_in, const int* in_sizes, int n_in,
                              void* d_out, int out_size, void* d_ws, size_t ws_size,
                              hipStream_t stream) {
    const float* x      = (const float*)d_in[0];
    const float* conv_w = (const float*)d_in[1];
    const float* gamma  = (const float*)d_in[2];
    const float* beta   = (const float*)d_in[3];
    const float* mean   = (const float*)d_in[4];
    const float* var    = (const float*)d_in[5];
    float* out = (float*)d_out;

    __bf16* Wt    = (__bf16*)d_ws;
    float*  biasp = (float*)((char*)d_ws + BIAS_OFF);
    __bf16* feat  = (__bf16*)((char*)d_ws + FEAT_OFF);

    void* args[] = {(void*)&x, (void*)&conv_w, (void*)&gamma, (void*)&beta,
                    (void*)&mean, (void*)&var, (void*)&Wt, (void*)&biasp,
                    (void*)&feat, (void*)&out};
    hipError_t e = hipLaunchCooperativeKernel((void*)fused_kernel,
                                              dim3(512), dim3(256),
                                              args, 0, stream);
    if (e != hipSuccess) {
        (void)hipGetLastError();   // clear sticky error, fall back
        prep_feat_kernel<<<FEAT_BLOCKS + PREP_BLOCKS, 256, 0, stream>>>(
            x, conv_w, gamma, beta, mean, var, Wt, biasp, feat);
        gemm_kernel<<<(OUTCH / 144) * (MTOT / 256), 256, 0, stream>>>(feat, Wt, biasp, x, out);
    }
}

// Round 3
// 118.820 us; speedup vs baseline: 2.5845x; 2.5845x over previous
//
#include <hip/hip_runtime.h>
#include <math.h>

typedef __bf16 v8bf __attribute__((ext_vector_type(8)));
typedef float  v4f  __attribute__((ext_vector_type(4)));

constexpr int Bsz  = 8;
constexpr int Cch  = 32;
constexpr int WIMG = 128;
constexpr int OH   = 64;
constexpr int OW   = 64;
constexpr int INCH = 201;
constexpr int KP   = 224;
constexpr int NK   = 7;
constexpr int OUTCH = 1152;
constexpr int MTOT = Bsz * OH * OW;   // 32768
constexpr float BN_EPS = 1e-5f;

// ws layout
constexpr size_t WT_BYTES = (size_t)NK * OUTCH * 32 * 2;   // 516,096
constexpr size_t BIAS_OFF = WT_BYTES;
constexpr size_t FEAT_OFF = BIAS_OFF + OUTCH * 4;          // 520,704 (16-aligned)

// ---- async global->LDS (wave-uniform base + lane*16 contiguous) ----
typedef const void __attribute__((address_space(1)))* gas_ptr;
typedef void __attribute__((address_space(3)))* las_ptr;
__device__ __forceinline__ void load16_lds(const void* g, void* l) {
    __builtin_amdgcn_global_load_lds((gas_ptr)(uintptr_t)g, (las_ptr)(uintptr_t)l, 16, 0, 0);
}

// ---------------------------------------------------------------------------
// K1: fused prep (blocks >= 512) + feat (blocks 0..511).  (round-0 verbatim)
// ---------------------------------------------------------------------------
constexpr int SXS = 132;            // padded sx row stride (floats)
constexpr int FEAT_BLOCKS = Bsz * OH;        // 512
constexpr int NPREP = OUTCH * KP + OUTCH;    // 259,200
constexpr int PREP_BLOCKS = (NPREP + 255) / 256;

__global__ __launch_bounds__(256)
void prep_feat_kernel(const float* __restrict__ x,
                      const float* __restrict__ conv_w,
                      const float* __restrict__ gamma,
                      const float* __restrict__ beta,
                      const float* __restrict__ mean,
                      const float* __restrict__ var,
                      __bf16* __restrict__ Wt,
                      float* __restrict__ biasp,
                      __bf16* __restrict__ feat) {
    __shared__ __align__(16) float sx[Cch * 3 * SXS];     // 50,688 B
    __shared__ __align__(16) float cmax[3 * SXS];         //  1,584 B
    __shared__ __align__(16) __bf16 sfeat[NK * OW * 32];  // 28,672 B

    const int t = threadIdx.x;

    if (blockIdx.x >= FEAT_BLOCKS) {
        // ---- prep part ----
        int idx = ((int)blockIdx.x - FEAT_BLOCKS) * 256 + t;
        const int nW = OUTCH * KP;
        if (idx < nW) {
            int o = idx / KP;
            int f = idx - o * KP;
            float inv = gamma[o] * rsqrtf(var[o] + BN_EPS);
            float v = (f < INCH) ? conv_w[o * INCH + f] * inv : 0.0f;
            Wt[((size_t)(f >> 5) * OUTCH + o) * 32 + (f & 31)] = (__bf16)v;
        } else if (idx < nW + OUTCH) {
            int o = idx - nW;
            float inv = gamma[o] * rsqrtf(var[o] + BN_EPS);
            biasp[o] = beta[o] - mean[o] * inv;
        }
        return;
    }

    // ---- feat part ----
    const int b  = blockIdx.x >> 6;
    const int ho = blockIdx.x & 63;

    // stage 1: float4 loads (12/thread), 3 rows x 32 ch
    for (int idx = t; idx < Cch * 3 * 32; idx += 256) {
        int c   = idx / 96;
        int rem = idx - c * 96;
        int i   = rem >> 5;
        int q   = rem & 31;
        int r   = 2 * ho - 1 + i;
        float4 v = make_float4(0.f, 0.f, 0.f, 0.f);
        if (r >= 0 && r < WIMG)
            v = *(const float4*)(x + (((size_t)(b * Cch + c) * WIMG) + r) * WIMG + q * 4);
        float* dst = sx + (c * 3 + i) * SXS + q * 4 + 1;
        dst[0] = v.x; dst[1] = v.y; dst[2] = v.z; dst[3] = v.w;
    }
    if (t < 96) {
        float* row = sx + t * SXS;
        row[0] = 0.0f; row[129] = 0.0f; row[130] = 0.0f; row[131] = 0.0f;
    }
    __syncthreads();

    if (t < 99) {     // column max over 32 channels (x1 source)
        int i = t / 33, cg = t - i * 33;
        const float4* base = (const float4*)sx + i * (SXS / 4) + cg;
        float4 m = base[0];
        #pragma unroll 4
        for (int c = 1; c < Cch; ++c) {
            float4 v = base[(size_t)c * (3 * SXS / 4)];
            m.x = fmaxf(m.x, v.x); m.y = fmaxf(m.y, v.y);
            m.z = fmaxf(m.z, v.z); m.w = fmaxf(m.w, v.w);
        }
        ((float4*)cmax)[i * (SXS / 4) + cg] = m;
    }
    __syncthreads();

    for (int idx = t; idx < 9 * 64; idx += 256) {     // x1
        int f = idx >> 6, wo = idx & 63;
        int i = f / 3, j = f - 3 * i;
        sfeat[wo * 32 + f] = (__bf16)cmax[i * SXS + 2 * wo + j];
    }
    {   // x2/x3
        const int wp = t & 31, g = t >> 5;
        const int wo0 = 2 * wp;
        #pragma unroll
        for (int cl = 0; cl < 4; ++cl) {
            int c = g * 4 + cl;
            float v[3][5];
            #pragma unroll
            for (int i = 0; i < 3; ++i) {
                const float* row = sx + (c * 3 + i) * SXS + 4 * wp;
                float4 q = *(const float4*)row;
                v[i][0] = q.x; v[i][1] = q.y; v[i][2] = q.z; v[i][3] = q.w;
                v[i][4] = row[4];
            }
            #pragma unroll
            for (int i = 0; i < 3; ++i) {            // x3
                int f = 105 + c * 3 + i;
                float a0 = fmaxf(fmaxf(v[i][0], v[i][1]), v[i][2]);
                float a1 = fmaxf(fmaxf(v[i][2], v[i][3]), v[i][4]);
                sfeat[(f >> 5) * 2048 + wo0 * 32 + (f & 31)]       = (__bf16)a0;
                sfeat[(f >> 5) * 2048 + (wo0 + 1) * 32 + (f & 31)] = (__bf16)a1;
            }
            #pragma unroll
            for (int j = 0; j < 3; ++j) {            // x2
                int f = 9 + c * 3 + j;
                float a0 = fmaxf(fmaxf(v[0][j], v[1][j]), v[2][j]);
                float a1 = fmaxf(fmaxf(v[0][j + 2], v[1][j + 2]), v[2][j + 2]);
                sfeat[(f >> 5) * 2048 + wo0 * 32 + (f & 31)]       = (__bf16)a0;
                sfeat[(f >> 5) * 2048 + (wo0 + 1) * 32 + (f & 31)] = (__bf16)a1;
            }
        }
    }
    for (int idx = t; idx < 64 * 23; idx += 256) {   // K padding
        int wo = idx / 23, fo = idx - wo * 23;
        int f = 201 + fo;
        sfeat[6 * 2048 + wo * 32 + (f & 31)] = (__bf16)0.0f;
    }
    __syncthreads();

    const size_t spat0 = (size_t)(b * OH + ho) * OW;
    #pragma unroll
    for (int kc = 0; kc < NK; ++kc) {
        float4 vv = ((const float4*)sfeat)[kc * 256 + t];
        ((float4*)((char*)feat + ((size_t)kc * MTOT + spat0) * 64))[t] = vv;
    }
}

// ---------------------------------------------------------------------------
// K2: gemm, M128 x N144 tile (round-0 geometry), with two changes:
//  (1) A-direct-to-registers: A fragments are wave-private contiguous 64B
//      rows -> load straight to VGPRs (coalesced dwordx4, 1-ahead prefetch;
//      the per-ks barrier's vmcnt(0) drain completes them for free).
//      Removes A's global_load_lds + 8/44 ds_read_b128 per block-ks and
//      shrinks LDS to 38.4 KB. acc[2][9]=72 regs; total ~115-125 -> chance
//      of 4 waves/SIMD (was ~145 -> 3).
//  (2) Epilogue YS 148->150 + float2 reads: read-bank starts 8 -> 16
//      (wl*150 % 32 = 22*wl, gcd 2), ~4-way instead of ~8-way conflicts;
//      writes stay 2-way-free (quad*600 % 32 in {0,24,16,8}).
// ---------------------------------------------------------------------------
constexpr int YS  = 150;            // y row stride (floats)
constexpr int REG = 16 * YS;        // per-wave y region (floats) = 9,600 B
__global__ __launch_bounds__(256, 2)
void gemm_kernel(const __bf16* __restrict__ feat,
                 const __bf16* __restrict__ Wt,
                 const float* __restrict__ biasp,
                 const float* __restrict__ x,
                 float* __restrict__ out) {
    __shared__ __align__(16) unsigned char lds[38400];
    // main loop: B dbuf @0 (2x9,216 = 18,432); epilogue y @0 (4x9,600)

    const int t    = threadIdx.x;
    const int nb   = (int)blockIdx.x >> 8;   // 0..7
    const int mb   = (int)blockIdx.x & 255;  // 0..255
    const int M0   = mb * 128;
    const int N0   = nb * 144;
    const int wave = t >> 6, lane = t & 63, quad = lane >> 4, l16 = lane & 15;

    auto issueB = [&](int ks, int buf) {
        const char* Bg = (const char*)Wt + ((size_t)ks * OUTCH + N0) * 64;
        char* Bb = (char*)lds + buf * 9216;
        #pragma unroll
        for (int i = 0; i < 2; ++i) {
            int off = (wave * 2 + i) * 1024 + lane * 16;
            load16_lds(Bg + off, Bb + off);
        }
        if (wave == 0) {
            int off2 = 8192 + lane * 16;
            load16_lds(Bg + off2, Bb + off2);
        }
    };
    // A fragment rows for this wave: M0 + wave*32 + mt*16 + l16, 16B at quad*16
    auto loadA = [&](int ks, v8bf af[2]) {
        const char* Ag = (const char*)feat +
            ((size_t)ks * MTOT + M0 + wave * 32 + l16) * 64 + quad * 16;
        af[0] = *(const v8bf*)(Ag);
        af[1] = *(const v8bf*)(Ag + 16 * 64);
    };

    v4f acc[2][9];
    #pragma unroll
    for (int mt = 0; mt < 2; ++mt)
        #pragma unroll
        for (int nt = 0; nt < 9; ++nt)
            acc[mt][nt] = (v4f){0.f, 0.f, 0.f, 0.f};

    v8bf afc[2], afn[2];
    loadA(0, afc);
    issueB(0, 0);
    __syncthreads();

    for (int ks = 0; ks < NK; ++ks) {
        const int cur = ks & 1;
        if (ks + 1 < NK) {
            issueB(ks + 1, cur ^ 1);
            loadA(ks + 1, afn);
        }

        const char* Bb = (const char*)lds + cur * 9216;
        #pragma unroll
        for (int nt = 0; nt < 9; ++nt) {
            v8bf bf = *(const v8bf*)(Bb + (nt * 16 + l16) * 64 + quad * 16);
            #pragma unroll
            for (int mt = 0; mt < 2; ++mt)
                acc[mt][nt] = __builtin_amdgcn_mfma_f32_16x16x32_bf16(
                    afc[mt], bf, acc[mt][nt], 0, 0, 0);
        }
        __syncthreads();   // drains global_load_lds (B) + guards dbuf/epilogue
        afc[0] = afn[0];
        afc[1] = afn[1];
    }

    // ---- epilogue: per-wave private transpose; no cross-wave barriers ----
    float bia[9];
    #pragma unroll
    for (int nt = 0; nt < 9; ++nt) bia[nt] = biasp[N0 + nt * 16 + l16];

    float* yw = (float*)lds + wave * REG;        // private [16][YS]
    const int cl  = lane >> 4;                   // 0..3 channel-sub
    const int wl  = lane & 15;                   // wo within 16-block
    const int cg  = nb * 4 + cl;
    const float s9 = 1.0f / 9.0f;

    #pragma unroll
    for (int p = 0; p < 2; ++p) {
        // produce: this wave's M-tile p (rows quad*4+r, cols nt*16+l16)
        #pragma unroll
        for (int nt = 0; nt < 9; ++nt)
            #pragma unroll
            for (int r = 0; r < 4; ++r)
                yw[(quad * 4 + r) * YS + nt * 16 + l16] =
                    fmaxf(acc[p][nt][r] + bia[nt], 0.0f);

        // consume: lane -> global row M0 + wave*32 + p*16 + wl
        const int mg  = M0 + wave * 32 + p * 16 + wl;
        const int bb  = mg >> 12;
        const int hob = (mg >> 6) & 63;
        const int wo  = mg & 63;
        const float* xc = x + (size_t)(bb * Cch + cg) * WIMG * WIMG;

        float pt[9];
        #pragma unroll
        for (int qi = 0; qi < 3; ++qi) {
            int r = 2 * hob - 1 + qi;
            #pragma unroll
            for (int qj = 0; qj < 3; ++qj) {
                int col = 2 * wo - 1 + qj;
                float v = 0.0f;
                if (r >= 0 && r < WIMG && col >= 0 && col < WIMG)
                    v = xc[r * WIMG + col];
                pt[qi * 3 + qj] = v;
            }
        }
        const float2* yrow = (const float2*)(yw + wl * YS + cl * 36);
        float o00 = 0.f, o01 = 0.f, o10 = 0.f, o11 = 0.f;
        #pragma unroll
        for (int q = 0; q < 9; ++q) {
            float2 y0 = yrow[2 * q];
            float2 y1 = yrow[2 * q + 1];
            float pq = pt[q];
            o00 = fmaf(pq, y0.x, o00);
            o01 = fmaf(pq, y0.y, o01);
            o10 = fmaf(pq, y1.x, o10);
            o11 = fmaf(pq, y1.y, o11);
        }
        size_t obase = (((size_t)(bb * Cch + cg) * WIMG) + 2 * hob) * WIMG + 2 * wo;
        *(float2*)(out + obase)        = make_float2(o00 * s9, o01 * s9);
        *(float2*)(out + obase + WIMG) = make_float2(o10 * s9, o11 * s9);
    }
}

extern "C" void kernel_launch(void* const* d_in, const int* in_sizes, int n_in,
                              void* d_out, int out_size, void* d_ws, size_t ws_size,
                              hipStream_t stream) {
    const float* x      = (const float*)d_in[0];
    const float* conv_w = (const float*)d_in[1];
    const float* gamma  = (const float*)d_in[2];
    const float* beta   = (const float*)d_in[3];
    const float* mean   = (const float*)d_in[4];
    const float* var    = (const float*)d_in[5];
    float* out = (float*)d_out;

    __bf16* Wt    = (__bf16*)d_ws;
    float*  biasp = (float*)((char*)d_ws + BIAS_OFF);
    __bf16* feat  = (__bf16*)((char*)d_ws + FEAT_OFF);

    prep_feat_kernel<<<FEAT_BLOCKS + PREP_BLOCKS, 256, 0, stream>>>(
        x, conv_w, gamma, beta, mean, var, Wt, biasp, feat);
    gemm_kernel<<<(OUTCH / 144) * (MTOT / 128), 256, 0, stream>>>(feat, Wt, biasp, x, out);
}

// Round 4
// 112.822 us; speedup vs baseline: 2.7219x; 1.0532x over previous
//
#include <hip/hip_runtime.h>
#include <math.h>

typedef __bf16 v8bf __attribute__((ext_vector_type(8)));
typedef float  v4f  __attribute__((ext_vector_type(4)));

constexpr int Bsz  = 8;
constexpr int Cch  = 32;
constexpr int WIMG = 128;
constexpr int OH   = 64;
constexpr int OW   = 64;
constexpr int INCH = 201;
constexpr int KP   = 224;
constexpr int NK   = 7;
constexpr int OUTCH = 1152;
constexpr int MTOT = Bsz * OH * OW;   // 32768
constexpr float BN_EPS = 1e-5f;

// ws layout
constexpr size_t WT_BYTES = (size_t)NK * OUTCH * 32 * 2;   // 516,096
constexpr size_t BIAS_OFF = WT_BYTES;
constexpr size_t FEAT_OFF = BIAS_OFF + OUTCH * 4;          // 520,704 (16-aligned)

// ---- async global->LDS (wave-uniform base + lane*16 contiguous) ----
typedef const void __attribute__((address_space(1)))* gas_ptr;
typedef void __attribute__((address_space(3)))* las_ptr;
__device__ __forceinline__ void load16_lds(const void* g, void* l) {
    __builtin_amdgcn_global_load_lds((gas_ptr)(uintptr_t)g, (las_ptr)(uintptr_t)l, 16, 0, 0);
}

// ---------------------------------------------------------------------------
// K1: prep. Half-row feat blocks (32 outputs each) for occupancy:
// LDS = sx 25,344 + sfeat 14,336 = 39,680 B -> 4 blocks/CU (was 80,944 -> 2).
// 1024 feat blocks at 4/CU = one co-resident generation, 16 waves/CU, and
// each barrier-separated serial phase is half as long. cmax buffer removed
// (x1 column-max computed directly from sx). Wt part unchanged, grid-appended.
// ---------------------------------------------------------------------------
constexpr int SX2 = 66;                       // sx row stride (floats)
constexpr int FEAT_BLOCKS = Bsz * OH * 2;     // 1024 half-row blocks
constexpr int NPREP = OUTCH * KP + OUTCH;     // 259,200
constexpr int PREP_BLOCKS = (NPREP + 255) / 256;

__global__ __launch_bounds__(256)
void prep_feat_kernel(const float* __restrict__ x,
                      const float* __restrict__ conv_w,
                      const float* __restrict__ gamma,
                      const float* __restrict__ beta,
                      const float* __restrict__ mean,
                      const float* __restrict__ var,
                      __bf16* __restrict__ Wt,
                      float* __restrict__ biasp,
                      __bf16* __restrict__ feat) {
    __shared__ __align__(16) float  sx[Cch * 3 * SX2];    // 25,344 B
    __shared__ __align__(16) __bf16 sfeat[NK * 32 * 32];  // 14,336 B

    const int t = threadIdx.x;

    if (blockIdx.x >= FEAT_BLOCKS) {
        // ---- Wt / bias prep ----
        int idx = ((int)blockIdx.x - FEAT_BLOCKS) * 256 + t;
        const int nW = OUTCH * KP;
        if (idx < nW) {
            int o = idx / KP;
            int f = idx - o * KP;
            float inv = gamma[o] * rsqrtf(var[o] + BN_EPS);
            float v = (f < INCH) ? conv_w[o * INCH + f] * inv : 0.0f;
            Wt[((size_t)(f >> 5) * OUTCH + o) * 32 + (f & 31)] = (__bf16)v;
        } else if (idx < nW + OUTCH) {
            int o = idx - nW;
            float inv = gamma[o] * rsqrtf(var[o] + BN_EPS);
            biasp[o] = beta[o] - mean[o] * inv;
        }
        return;
    }

    // ---- feat half-row: b, ho, half (32 outputs) ----
    const int b    = blockIdx.x >> 7;
    const int rem  = blockIdx.x & 127;
    const int ho   = rem >> 1;
    const int half = rem & 1;
    const int ci0  = 64 * half;      // input col of local index l=1
    const int w0o  = 32 * half;      // output wo base
    // local l in [0,66): global input col = ci0 - 1 + l
    // output v in [0,32): 3x3 window cols -> local idx 2v+j

    // stage 1: main body, float4 loads (6/thread): l = 1..64
    for (int idx = t; idx < Cch * 3 * 16; idx += 256) {
        int c    = idx / 48;
        int rrem = idx - c * 48;
        int i    = rrem >> 4;
        int q    = rrem & 15;
        int r    = 2 * ho - 1 + i;
        float4 v = make_float4(0.f, 0.f, 0.f, 0.f);
        if (r >= 0 && r < WIMG)
            v = *(const float4*)(x + (((size_t)(b * Cch + c) * WIMG) + r) * WIMG + ci0 + 4 * q);
        float* dst = sx + (c * 3 + i) * SX2 + 1 + 4 * q;
        dst[0] = v.x; dst[1] = v.y; dst[2] = v.z; dst[3] = v.w;
    }
    // stage 1b: halo cols l=0 (col ci0-1) and l=65 (col ci0+64)
    if (t < 96) {
        int c = t / 3, i = t - 3 * (t / 3);
        int r = 2 * ho - 1 + i;
        float lv = 0.f, rv = 0.f;
        if (r >= 0 && r < WIMG) {
            const float* xr = x + (((size_t)(b * Cch + c) * WIMG) + r) * WIMG;
            if (half) lv = xr[63];   // col 63 exists; right col 128 OOB
            else      rv = xr[64];   // left col -1 OOB; col 64 exists
        }
        float* row = sx + (c * 3 + i) * SX2;
        row[0] = lv; row[65] = rv;
    }
    __syncthreads();

    // stage 2: x1 = column max over 32 channels, written direct (f=3i+j)
    for (int idx = t; idx < 9 * 32; idx += 256) {
        int f = idx >> 5, v = idx & 31;
        int i = f / 3, j = f - 3 * i;
        const float* p = sx + i * SX2 + 2 * v + j;
        float m = p[0];
        #pragma unroll 4
        for (int c = 1; c < Cch; ++c) m = fmaxf(m, p[c * (3 * SX2)]);
        sfeat[v * 32 + f] = (__bf16)m;
    }
    // stage 3: x2/x3 (one output v=wp per lane, 4 channels per thread)
    {
        const int wp = t & 31, g = t >> 5;
        #pragma unroll
        for (int cl = 0; cl < 4; ++cl) {
            int c = g * 4 + cl;
            float w[3][3];
            #pragma unroll
            for (int i = 0; i < 3; ++i) {
                const float* row = sx + (c * 3 + i) * SX2 + 2 * wp;
                float2 q2 = *(const float2*)row;
                w[i][0] = q2.x; w[i][1] = q2.y; w[i][2] = row[2];
            }
            #pragma unroll
            for (int i = 0; i < 3; ++i) {            // x3: max over cols j
                int f = 105 + c * 3 + i;
                float a = fmaxf(fmaxf(w[i][0], w[i][1]), w[i][2]);
                sfeat[(f >> 5) * 1024 + wp * 32 + (f & 31)] = (__bf16)a;
            }
            #pragma unroll
            for (int j = 0; j < 3; ++j) {            // x2: max over rows i
                int f = 9 + c * 3 + j;
                float a = fmaxf(fmaxf(w[0][j], w[1][j]), w[2][j]);
                sfeat[(f >> 5) * 1024 + wp * 32 + (f & 31)] = (__bf16)a;
            }
        }
    }
    // K padding f = 201..223 (kc 6, slots 9..31)
    for (int idx = t; idx < 23 * 32; idx += 256) {
        int v = idx / 23, fo = idx - 23 * v;
        sfeat[6 * 1024 + v * 32 + 9 + fo] = (__bf16)0.0f;
    }
    __syncthreads();

    // stage 5: sfeat -> feat (coalesced float4)
    const size_t m0 = (size_t)(b * OH + ho) * OW + w0o;
    for (int idx = t; idx < NK * 128; idx += 256) {
        int kc = idx >> 7, r = idx & 127;
        int v = r >> 2, part = r & 3;
        float4 vv = ((const float4*)sfeat)[idx];
        ((float4*)((char*)feat + ((size_t)kc * MTOT + m0 + v) * 64))[part] = vv;
    }
}

// ---------------------------------------------------------------------------
// K2: gemm, M128 x N144 (round-3 body). Change: __launch_bounds__(256, 4)
// caps VGPR at 128 -> 4 blocks/CU (LDS 38.4KB x4 = 153.6KB fits). Register
// arithmetic: acc 72 + afc/afn 16 + bf 8 + bia 9 + addr ~15 ~= 120 live.
// If this spills, expect a round-2-style regression -> revert.
// ---------------------------------------------------------------------------
constexpr int YS  = 150;            // y row stride (floats)
constexpr int REG = 16 * YS;        // per-wave y region (floats) = 9,600 B
__global__ __launch_bounds__(256, 4)
void gemm_kernel(const __bf16* __restrict__ feat,
                 const __bf16* __restrict__ Wt,
                 const float* __restrict__ biasp,
                 const float* __restrict__ x,
                 float* __restrict__ out) {
    __shared__ __align__(16) unsigned char lds[38400];
    // main loop: B dbuf @0 (2x9,216 = 18,432); epilogue y @0 (4x9,600)

    const int t    = threadIdx.x;
    const int nb   = (int)blockIdx.x >> 8;   // 0..7
    const int mb   = (int)blockIdx.x & 255;  // 0..255
    const int M0   = mb * 128;
    const int N0   = nb * 144;
    const int wave = t >> 6, lane = t & 63, quad = lane >> 4, l16 = lane & 15;

    auto issueB = [&](int ks, int buf) {
        const char* Bg = (const char*)Wt + ((size_t)ks * OUTCH + N0) * 64;
        char* Bb = (char*)lds + buf * 9216;
        #pragma unroll
        for (int i = 0; i < 2; ++i) {
            int off = (wave * 2 + i) * 1024 + lane * 16;
            load16_lds(Bg + off, Bb + off);
        }
        if (wave == 0) {
            int off2 = 8192 + lane * 16;
            load16_lds(Bg + off2, Bb + off2);
        }
    };
    // A fragment rows for this wave: M0 + wave*32 + mt*16 + l16, 16B at quad*16
    auto loadA = [&](int ks, v8bf af[2]) {
        const char* Ag = (const char*)feat +
            ((size_t)ks * MTOT + M0 + wave * 32 + l16) * 64 + quad * 16;
        af[0] = *(const v8bf*)(Ag);
        af[1] = *(const v8bf*)(Ag + 16 * 64);
    };

    v4f acc[2][9];
    #pragma unroll
    for (int mt = 0; mt < 2; ++mt)
        #pragma unroll
        for (int nt = 0; nt < 9; ++nt)
            acc[mt][nt] = (v4f){0.f, 0.f, 0.f, 0.f};

    v8bf afc[2], afn[2];
    loadA(0, afc);
    issueB(0, 0);
    __syncthreads();

    for (int ks = 0; ks < NK; ++ks) {
        const int cur = ks & 1;
        if (ks + 1 < NK) {
            issueB(ks + 1, cur ^ 1);
            loadA(ks + 1, afn);
        }

        const char* Bb = (const char*)lds + cur * 9216;
        #pragma unroll
        for (int nt = 0; nt < 9; ++nt) {
            v8bf bf = *(const v8bf*)(Bb + (nt * 16 + l16) * 64 + quad * 16);
            #pragma unroll
            for (int mt = 0; mt < 2; ++mt)
                acc[mt][nt] = __builtin_amdgcn_mfma_f32_16x16x32_bf16(
                    afc[mt], bf, acc[mt][nt], 0, 0, 0);
        }
        __syncthreads();   // drains global_load_lds (B) + guards dbuf/epilogue
        afc[0] = afn[0];
        afc[1] = afn[1];
    }

    // ---- epilogue: per-wave private transpose; no cross-wave barriers ----
    float bia[9];
    #pragma unroll
    for (int nt = 0; nt < 9; ++nt) bia[nt] = biasp[N0 + nt * 16 + l16];

    float* yw = (float*)lds + wave * REG;        // private [16][YS]
    const int cl  = lane >> 4;                   // 0..3 channel-sub
    const int wl  = lane & 15;                   // wo within 16-block
    const int cg  = nb * 4 + cl;
    const float s9 = 1.0f / 9.0f;

    #pragma unroll
    for (int p = 0; p < 2; ++p) {
        // produce: this wave's M-tile p (rows quad*4+r, cols nt*16+l16)
        #pragma unroll
        for (int nt = 0; nt < 9; ++nt)
            #pragma unroll
            for (int r = 0; r < 4; ++r)
                yw[(quad * 4 + r) * YS + nt * 16 + l16] =
                    fmaxf(acc[p][nt][r] + bia[nt], 0.0f);

        // consume: lane -> global row M0 + wave*32 + p*16 + wl
        const int mg  = M0 + wave * 32 + p * 16 + wl;
        const int bb  = mg >> 12;
        const int hob = (mg >> 6) & 63;
        const int wo  = mg & 63;
        const float* xc = x + (size_t)(bb * Cch + cg) * WIMG * WIMG;

        float pt[9];
        #pragma unroll
        for (int qi = 0; qi < 3; ++qi) {
            int r = 2 * hob - 1 + qi;
            #pragma unroll
            for (int qj = 0; qj < 3; ++qj) {
                int col = 2 * wo - 1 + qj;
                float v = 0.0f;
                if (r >= 0 && r < WIMG && col >= 0 && col < WIMG)
                    v = xc[r * WIMG + col];
                pt[qi * 3 + qj] = v;
            }
        }
        const float2* yrow = (const float2*)(yw + wl * YS + cl * 36);
        float o00 = 0.f, o01 = 0.f, o10 = 0.f, o11 = 0.f;
        #pragma unroll
        for (int q = 0; q < 9; ++q) {
            float2 y0 = yrow[2 * q];
            float2 y1 = yrow[2 * q + 1];
            float pq = pt[q];
            o00 = fmaf(pq, y0.x, o00);
            o01 = fmaf(pq, y0.y, o01);
            o10 = fmaf(pq, y1.x, o10);
            o11 = fmaf(pq, y1.y, o11);
        }
        size_t obase = (((size_t)(bb * Cch + cg) * WIMG) + 2 * hob) * WIMG + 2 * wo;
        *(float2*)(out + obase)        = make_float2(o00 * s9, o01 * s9);
        *(float2*)(out + obase + WIMG) = make_float2(o10 * s9, o11 * s9);
    }
}

extern "C" void kernel_launch(void* const* d_in, const int* in_sizes, int n_in,
                              void* d_out, int out_size, void* d_ws, size_t ws_size,
                              hipStream_t stream) {
    const float* x      = (const float*)d_in[0];
    const float* conv_w = (const float*)d_in[1];
    const float* gamma  = (const float*)d_in[2];
    const float* beta   = (const float*)d_in[3];
    const float* mean   = (const float*)d_in[4];
    const float* var    = (const float*)d_in[5];
    float* out = (float*)d_out;

    __bf16* Wt    = (__bf16*)d_ws;
    float*  biasp = (float*)((char*)d_ws + BIAS_OFF);
    __bf16* feat  = (__bf16*)((char*)d_ws + FEAT_OFF);

    prep_feat_kernel<<<FEAT_BLOCKS + PREP_BLOCKS, 256, 0, stream>>>(
        x, conv_w, gamma, beta, mean, var, Wt, biasp, feat);
    gemm_kernel<<<(OUTCH / 144) * (MTOT / 128), 256, 0, stream>>>(feat, Wt, biasp, x, out);
}

// Round 6
// 110.919 us; speedup vs baseline: 2.7686x; 1.0172x over previous
//
#include <hip/hip_runtime.h>
#include <math.h>

typedef __bf16 v8bf __attribute__((ext_vector_type(8)));
typedef float  v4f  __attribute__((ext_vector_type(4)));

constexpr int Bsz  = 8;
constexpr int Cch  = 32;
constexpr int WIMG = 128;
constexpr int OH   = 64;
constexpr int OW   = 64;
constexpr int INCH = 201;
constexpr int KP   = 224;
constexpr int NK   = 7;
constexpr int OUTCH = 1152;
constexpr int MTOT = Bsz * OH * OW;   // 32768
constexpr float BN_EPS = 1e-5f;

// ws layout
constexpr size_t WT_BYTES = (size_t)NK * OUTCH * 32 * 2;   // 516,096
constexpr size_t BIAS_OFF = WT_BYTES;
constexpr size_t FEAT_OFF = BIAS_OFF + OUTCH * 4;          // 520,704 (16-aligned)

// ---- async global->LDS (wave-uniform base + lane*16 contiguous) ----
typedef const void __attribute__((address_space(1)))* gas_ptr;
typedef void __attribute__((address_space(3)))* las_ptr;
__device__ __forceinline__ void load16_lds(const void* g, void* l) {
    __builtin_amdgcn_global_load_lds((gas_ptr)(uintptr_t)g, (las_ptr)(uintptr_t)l, 16, 0, 0);
}

// ---------------------------------------------------------------------------
// K1: prep. Quarter-row feat blocks (16 outputs each) for max occupancy:
// LDS = sx 13,056 + sfeat 7,168 = 20,224 B -> 8 blocks/CU.
// __launch_bounds__(256,8) caps VGPR at 64 -> 32 waves/CU (HW max).
// ROUND-5 BUG FIX (the single edit this round): K-padding was
// `if (t < 368)` with only 256 threads -> 112 sfeat slots left
// uninitialized (garbage bf16, incl. Inf/NaN patterns, entered the MFMA
// A-operand -> nondeterministic corruption). Now a grid-stride loop.
// ---------------------------------------------------------------------------
constexpr int SX4 = 34;                       // sx row stride (floats)
constexpr int FEAT_BLOCKS = Bsz * OH * 4;     // 2048 quarter-row blocks
constexpr int NPREP = OUTCH * KP + OUTCH;     // 259,200
constexpr int PREP_BLOCKS = (NPREP + 255) / 256;

__global__ __launch_bounds__(256, 8)
void prep_feat_kernel(const float* __restrict__ x,
                      const float* __restrict__ conv_w,
                      const float* __restrict__ gamma,
                      const float* __restrict__ beta,
                      const float* __restrict__ mean,
                      const float* __restrict__ var,
                      __bf16* __restrict__ Wt,
                      float* __restrict__ biasp,
                      __bf16* __restrict__ feat) {
    __shared__ __align__(16) float  sx[Cch * 3 * SX4];    // 13,056 B
    __shared__ __align__(16) __bf16 sfeat[NK * 16 * 32];  //  7,168 B

    const int t = threadIdx.x;

    if (blockIdx.x >= FEAT_BLOCKS) {
        // ---- Wt / bias prep ----
        int idx = ((int)blockIdx.x - FEAT_BLOCKS) * 256 + t;
        const int nW = OUTCH * KP;
        if (idx < nW) {
            int o = idx / KP;
            int f = idx - o * KP;
            float inv = gamma[o] * rsqrtf(var[o] + BN_EPS);
            float v = (f < INCH) ? conv_w[o * INCH + f] * inv : 0.0f;
            Wt[((size_t)(f >> 5) * OUTCH + o) * 32 + (f & 31)] = (__bf16)v;
        } else if (idx < nW + OUTCH) {
            int o = idx - nW;
            float inv = gamma[o] * rsqrtf(var[o] + BN_EPS);
            biasp[o] = beta[o] - mean[o] * inv;
        }
        return;
    }

    // ---- feat quarter-row: b, ho, qtr (16 outputs) ----
    const int b    = blockIdx.x >> 8;
    const int rem  = blockIdx.x & 255;
    const int ho   = rem >> 2;
    const int qtr  = rem & 3;
    const int ci0  = 32 * qtr;       // input col of local index l=1
    const int w0o  = 16 * qtr;       // output wo base
    // local l in [0,34): global input col = ci0 - 1 + l
    // output v in [0,16): 3x3 window cols -> local idx 2v+j

    // stage 1: main body, float4 loads (3/thread): cols ci0 .. ci0+31
    for (int idx = t; idx < Cch * 3 * 8; idx += 256) {
        int c    = idx / 24;
        int rrem = idx - c * 24;
        int i    = rrem >> 3;
        int q    = rrem & 7;
        int r    = 2 * ho - 1 + i;
        float4 v = make_float4(0.f, 0.f, 0.f, 0.f);
        if (r >= 0 && r < WIMG)
            v = *(const float4*)(x + (((size_t)(b * Cch + c) * WIMG) + r) * WIMG + ci0 + 4 * q);
        float* dst = sx + (c * 3 + i) * SX4 + 1 + 4 * q;
        dst[0] = v.x; dst[1] = v.y; dst[2] = v.z; dst[3] = v.w;
    }
    // stage 1b: halo cols l=0 (col ci0-1) and l=33 (col ci0+32)
    if (t < 96) {
        int c = t / 3, i = t - 3 * (t / 3);
        int r = 2 * ho - 1 + i;
        float lv = 0.f, rv = 0.f;
        if (r >= 0 && r < WIMG) {
            const float* xr = x + (((size_t)(b * Cch + c) * WIMG) + r) * WIMG;
            if (qtr > 0) lv = xr[ci0 - 1];
            if (qtr < 3) rv = xr[ci0 + 32];
        }
        float* row = sx + (c * 3 + i) * SX4;
        row[0] = lv; row[33] = rv;
    }
    __syncthreads();

    // stage 2: x1 = column max over 32 channels, written direct (f=3i+j)
    if (t < 9 * 16) {
        int f = t >> 4, v = t & 15;
        int i = f / 3, j = f - 3 * i;
        const float* p = sx + i * SX4 + 2 * v + j;
        float m = p[0];
        #pragma unroll 4
        for (int c = 1; c < Cch; ++c) m = fmaxf(m, p[c * (3 * SX4)]);
        sfeat[v * 32 + f] = (__bf16)m;
    }
    // stage 3: x2/x3 (one output v per lane-group, 2 channels per thread)
    {
        const int v = t & 15, g = t >> 4;     // g in [0,16)
        #pragma unroll
        for (int cl = 0; cl < 2; ++cl) {
            int c = g * 2 + cl;
            float w[3][3];
            #pragma unroll
            for (int i = 0; i < 3; ++i) {
                const float* row = sx + (c * 3 + i) * SX4 + 2 * v;
                float2 q2 = *(const float2*)row;
                w[i][0] = q2.x; w[i][1] = q2.y; w[i][2] = row[2];
            }
            #pragma unroll
            for (int i = 0; i < 3; ++i) {            // x3: max over cols j
                int f = 105 + c * 3 + i;
                float a = fmaxf(fmaxf(w[i][0], w[i][1]), w[i][2]);
                sfeat[(f >> 5) * 512 + v * 32 + (f & 31)] = (__bf16)a;
            }
            #pragma unroll
            for (int j = 0; j < 3; ++j) {            // x2: max over rows i
                int f = 9 + c * 3 + j;
                float a = fmaxf(fmaxf(w[0][j], w[1][j]), w[2][j]);
                sfeat[(f >> 5) * 512 + v * 32 + (f & 31)] = (__bf16)a;
            }
        }
    }
    // K padding f = 201..223 (kc 6, slots 9..31) — FIXED: full-coverage loop
    for (int idx = t; idx < 23 * 16; idx += 256) {
        int v = idx / 23, fo = idx - 23 * v;
        sfeat[6 * 512 + v * 32 + 9 + fo] = (__bf16)0.0f;
    }
    __syncthreads();

    // stage 5: sfeat -> feat (coalesced float4; 448 vec4 = 1.75/thread)
    const size_t m0 = (size_t)(b * OH + ho) * OW + w0o;
    for (int idx = t; idx < NK * 64; idx += 256) {
        int kc = idx >> 6, r = idx & 63;
        int v = r >> 2, part = r & 3;
        float4 vv = ((const float4*)sfeat)[idx];
        ((float4*)((char*)feat + ((size_t)kc * MTOT + m0 + v) * 64))[part] = vv;
    }
}

// ---------------------------------------------------------------------------
// K2: gemm, M128 x N144 (round-4 verbatim). __launch_bounds__(256, 4)
// caps VGPR at 128 -> 4 blocks/CU (LDS 38.4KB x4 = 153.6KB fits).
// ---------------------------------------------------------------------------
constexpr int YS  = 150;            // y row stride (floats)
constexpr int REG = 16 * YS;        // per-wave y region (floats) = 9,600 B
__global__ __launch_bounds__(256, 4)
void gemm_kernel(const __bf16* __restrict__ feat,
                 const __bf16* __restrict__ Wt,
                 const float* __restrict__ biasp,
                 const float* __restrict__ x,
                 float* __restrict__ out) {
    __shared__ __align__(16) unsigned char lds[38400];
    // main loop: B dbuf @0 (2x9,216 = 18,432); epilogue y @0 (4x9,600)

    const int t    = threadIdx.x;
    const int nb   = (int)blockIdx.x >> 8;   // 0..7
    const int mb   = (int)blockIdx.x & 255;  // 0..255
    const int M0   = mb * 128;
    const int N0   = nb * 144;
    const int wave = t >> 6, lane = t & 63, quad = lane >> 4, l16 = lane & 15;

    auto issueB = [&](int ks, int buf) {
        const char* Bg = (const char*)Wt + ((size_t)ks * OUTCH + N0) * 64;
        char* Bb = (char*)lds + buf * 9216;
        #pragma unroll
        for (int i = 0; i < 2; ++i) {
            int off = (wave * 2 + i) * 1024 + lane * 16;
            load16_lds(Bg + off, Bb + off);
        }
        if (wave == 0) {
            int off2 = 8192 + lane * 16;
            load16_lds(Bg + off2, Bb + off2);
        }
    };
    // A fragment rows for this wave: M0 + wave*32 + mt*16 + l16, 16B at quad*16
    auto loadA = [&](int ks, v8bf af[2]) {
        const char* Ag = (const char*)feat +
            ((size_t)ks * MTOT + M0 + wave * 32 + l16) * 64 + quad * 16;
        af[0] = *(const v8bf*)(Ag);
        af[1] = *(const v8bf*)(Ag + 16 * 64);
    };

    v4f acc[2][9];
    #pragma unroll
    for (int mt = 0; mt < 2; ++mt)
        #pragma unroll
        for (int nt = 0; nt < 9; ++nt)
            acc[mt][nt] = (v4f){0.f, 0.f, 0.f, 0.f};

    v8bf afc[2], afn[2];
    loadA(0, afc);
    issueB(0, 0);
    __syncthreads();

    for (int ks = 0; ks < NK; ++ks) {
        const int cur = ks & 1;
        if (ks + 1 < NK) {
            issueB(ks + 1, cur ^ 1);
            loadA(ks + 1, afn);
        }

        const char* Bb = (const char*)lds + cur * 9216;
        #pragma unroll
        for (int nt = 0; nt < 9; ++nt) {
            v8bf bf = *(const v8bf*)(Bb + (nt * 16 + l16) * 64 + quad * 16);
            #pragma unroll
            for (int mt = 0; mt < 2; ++mt)
                acc[mt][nt] = __builtin_amdgcn_mfma_f32_16x16x32_bf16(
                    afc[mt], bf, acc[mt][nt], 0, 0, 0);
        }
        __syncthreads();   // drains global_load_lds (B) + guards dbuf/epilogue
        afc[0] = afn[0];
        afc[1] = afn[1];
    }

    // ---- epilogue: per-wave private transpose; no cross-wave barriers ----
    float bia[9];
    #pragma unroll
    for (int nt = 0; nt < 9; ++nt) bia[nt] = biasp[N0 + nt * 16 + l16];

    float* yw = (float*)lds + wave * REG;        // private [16][YS]
    const int cl  = lane >> 4;                   // 0..3 channel-sub
    const int wl  = lane & 15;                   // wo within 16-block
    const int cg  = nb * 4 + cl;
    const float s9 = 1.0f / 9.0f;

    #pragma unroll
    for (int p = 0; p < 2; ++p) {
        // produce: this wave's M-tile p (rows quad*4+r, cols nt*16+l16)
        #pragma unroll
        for (int nt = 0; nt < 9; ++nt)
            #pragma unroll
            for (int r = 0; r < 4; ++r)
                yw[(quad * 4 + r) * YS + nt * 16 + l16] =
                    fmaxf(acc[p][nt][r] + bia[nt], 0.0f);

        // consume: lane -> global row M0 + wave*32 + p*16 + wl
        const int mg  = M0 + wave * 32 + p * 16 + wl;
        const int bb  = mg >> 12;
        const int hob = (mg >> 6) & 63;
        const int wo  = mg & 63;
        const float* xc = x + (size_t)(bb * Cch + cg) * WIMG * WIMG;

        float pt[9];
        #pragma unroll
        for (int qi = 0; qi < 3; ++qi) {
            int r = 2 * hob - 1 + qi;
            #pragma unroll
            for (int qj = 0; qj < 3; ++qj) {
                int col = 2 * wo - 1 + qj;
                float v = 0.0f;
                if (r >= 0 && r < WIMG && col >= 0 && col < WIMG)
                    v = xc[r * WIMG + col];
                pt[qi * 3 + qj] = v;
            }
        }
        const float2* yrow = (const float2*)(yw + wl * YS + cl * 36);
        float o00 = 0.f, o01 = 0.f, o10 = 0.f, o11 = 0.f;
        #pragma unroll
        for (int q = 0; q < 9; ++q) {
            float2 y0 = yrow[2 * q];
            float2 y1 = yrow[2 * q + 1];
            float pq = pt[q];
            o00 = fmaf(pq, y0.x, o00);
            o01 = fmaf(pq, y0.y, o01);
            o10 = fmaf(pq, y1.x, o10);
            o11 = fmaf(pq, y1.y, o11);
        }
        size_t obase = (((size_t)(bb * Cch + cg) * WIMG) + 2 * hob) * WIMG + 2 * wo;
        *(float2*)(out + obase)        = make_float2(o00 * s9, o01 * s9);
        *(float2*)(out + obase + WIMG) = make_float2(o10 * s9, o11 * s9);
    }
}

extern "C" void kernel_launch(void* const* d_in, const int* in_sizes, int n_in,
                              void* d_out, int out_size, void* d_ws, size_t ws_size,
                              hipStream_t stream) {
    const float* x      = (const float*)d_in[0];
    const float* conv_w = (const float*)d_in[1];
    const float* gamma  = (const float*)d_in[2];
    const float* beta   = (const float*)d_in[3];
    const float* mean   = (const float*)d_in[4];
    const float* var    = (const float*)d_in[5];
    float* out = (float*)d_out;

    __bf16* Wt    = (__bf16*)d_ws;
    float*  biasp = (float*)((char*)d_ws + BIAS_OFF);
    __bf16* feat  = (__bf16*)((char*)d_ws + FEAT_OFF);

    prep_feat_kernel<<<FEAT_BLOCKS + PREP_BLOCKS, 256, 0, stream>>>(
        x, conv_w, gamma, beta, mean, var, Wt, biasp, feat);
    gemm_kernel<<<(OUTCH / 144) * (MTOT / 128), 256, 0, stream>>>(feat, Wt, biasp, x, out);
}